// Round 7
// baseline (275.834 us; speedup 1.0000x reference)
//
#include <hip/hip_runtime.h>
#include <hip/hip_bf16.h>

typedef unsigned short u16;
typedef __attribute__((ext_vector_type(8))) __bf16 bf16x8;
typedef __attribute__((ext_vector_type(4))) float floatx4;

#define B_   16
#define N1_  4096
#define N2_  1024
#define C1_  128
#define C2_  256
#define CIN_ 384
#define CM_  256
#define CO_  128

__device__ __forceinline__ u16 f2bf(float f) {
  unsigned u = __float_as_uint(f);
  u = (u + 0x7fffu + ((u >> 16) & 1u)) >> 16;
  return (u16)u;
}
__device__ __forceinline__ float bf2f(u16 h) {
  return __uint_as_float(((unsigned)h) << 16);
}

union U128 { uint4 u; bf16x8 v; u16 s[8]; };

__device__ __forceinline__ bf16x8 ldfrag(const u16* p) {
  U128 x; x.u = *(const uint4*)p; return x.v;
}
__device__ __forceinline__ uint4 pack8(const u16* h) {
  uint4 u;
  u.x = (unsigned)h[0] | ((unsigned)h[1] << 16);
  u.y = (unsigned)h[2] | ((unsigned)h[3] << 16);
  u.z = (unsigned)h[4] | ((unsigned)h[5] << 16);
  u.w = (unsigned)h[6] | ((unsigned)h[7] << 16);
  return u;
}

// Tiled operand layout (MFMA-fragment-major):
//   frag(tile, kt) at [tile][kt][lane][8] u16, lane = quad*16+col,
//   element j = M[row=col][k = kt*32 + quad*8 + j]. Wave frag load = base + lane*16B.

// ---------------- K1a: 3-NN partial (128-cand chunk, 4 pts/thread) + castw side-job ----------------
// grid (5,16,8): x<4 -> knn (x = 1024-point block, y = batch, z = chunk);
//                x==4 -> weight cast (128 blocks, items 0..16383).
__global__ __launch_bounds__(256) void knn_part_kernel(
    const float* __restrict__ xyz1, const float* __restrict__ xyz2,
    float* __restrict__ pd, int* __restrict__ pi,
    const float* __restrict__ w0, const float* __restrict__ w1,
    u16* __restrict__ w0b, u16* __restrict__ w1b)
{
  __shared__ float4 sp[128];
  int t = threadIdx.x;
  if (blockIdx.x == 4) {                           // ---- castw side-job ----
    int item = (blockIdx.y * 8 + blockIdx.z) * 256 + t;   // 0..32767
    if (item < 12288) {                             // w0: 256 rows x 48 chunks
      int m = item / 48, kc = item % 48;
      const float* p = w0 + m * CIN_ + kc * 8;
      u16 h8[8];
      #pragma unroll
      for (int j = 0; j < 8; ++j) h8[j] = f2bf(p[j]);
      int mt = m >> 4, col = m & 15, kt = kc >> 2, quad = kc & 3;
      *(uint4*)(w0b + ((mt*12 + kt)*512 + (quad*16 + col)*8)) = pack8(h8);
    } else if (item < 16384) {                      // w1: 128 rows x 32 chunks
      int i2 = item - 12288;
      int m = i2 >> 5, kc = i2 & 31;
      const float* p = w1 + m * CM_ + kc * 8;
      u16 h8[8];
      #pragma unroll
      for (int j = 0; j < 8; ++j) h8[j] = f2bf(p[j]);
      int mt = m >> 4, col = m & 15, kt = kc >> 2, quad = kc & 3;
      *(uint4*)(w1b + ((mt*8 + kt)*512 + (quad*16 + col)*8)) = pack8(h8);
    }
    return;
  }
  // ---- knn ----
  int b = blockIdx.y, chunk = blockIdx.z;
  const float* p2 = xyz2 + ((size_t)b * N2_ + chunk * 128) * 3;
  if (t < 128) sp[t] = make_float4(p2[t*3], p2[t*3+1], p2[t*3+2], 0.f);
  __syncthreads();
  int pbase = blockIdx.x * 1024 + t;               // + k*256, k=0..3
  float px[4], py[4], pz[4];
  float d0[4], d1[4], d2[4];
  int   i0[4], i1[4], i2[4];
  #pragma unroll
  for (int k = 0; k < 4; ++k) {
    const float* q = xyz1 + ((size_t)b * N1_ + pbase + k*256) * 3;
    px[k] = q[0]; py[k] = q[1]; pz[k] = q[2];
    d0[k] = 1e30f; d1[k] = 1e30f; d2[k] = 1e30f;
    i0[k] = 0; i1[k] = 0; i2[k] = 0;
  }
  int jb = chunk * 128;
  for (int j = 0; j < 128; ++j) {
    float4 c = sp[j];                              // broadcast: conflict-free
    int jj = jb + j;
    #pragma unroll
    for (int k = 0; k < 4; ++k) {
      float dx = px[k] - c.x, dy = py[k] - c.y, dz = pz[k] - c.z;
      float d = fmaf(dx, dx, fmaf(dy, dy, dz*dz));
      bool c2 = d < d2[k], c1 = d < d1[k], c0 = d < d0[k];
      d2[k] = c1 ? d1[k] : (c2 ? d  : d2[k]);
      i2[k] = c1 ? i1[k] : (c2 ? jj : i2[k]);
      d1[k] = c0 ? d0[k] : (c1 ? d  : d1[k]);
      i1[k] = c0 ? i0[k] : (c1 ? jj : i1[k]);
      d0[k] = c0 ? d  : d0[k];
      i0[k] = c0 ? jj : i0[k];
    }
  }
  #pragma unroll
  for (int k = 0; k < 4; ++k) {
    int o = chunk*65536 + b*4096 + pbase + k*256;
    pd[o] = d0[k]; pd[o + 524288] = d1[k]; pd[o + 1048576] = d2[k];
    pi[o] = i0[k]; pi[o + 524288] = i1[k]; pi[o + 1048576] = i2[k];
  }
}

// ---------------- K1b: merge 8 chunk-triples -> final idx/weights ----------------
__global__ __launch_bounds__(256) void knn_merge_kernel(
    const float* __restrict__ pd, const int* __restrict__ pi,
    int* __restrict__ idx_out, float* __restrict__ w_out)
{
  int p = blockIdx.x * 256 + threadIdx.x;          // p = b*4096 + i, 0..65535
  float d0 = 1e30f, d1 = 1e30f, d2 = 1e30f;
  int i0 = 0, i1 = 0, i2 = 0;
  #pragma unroll
  for (int c = 0; c < 8; ++c) {                    // ascending-j chunk order: stable
    int o = c*65536 + p;
    #pragma unroll
    for (int k = 0; k < 3; ++k) {
      float d = pd[o + k*524288];
      int ix = pi[o + k*524288];
      if (d < d2) {
        if (d < d0)      { d2=d1; i2=i1; d1=d0; i1=i0; d0=d; i0=ix; }
        else if (d < d1) { d2=d1; i2=i1; d1=d;  i1=ix; }
        else             { d2=d;  i2=ix; }
      }
    }
  }
  float w0 = 1.f/(d0+1e-8f), w1 = 1.f/(d1+1e-8f), w2 = 1.f/(d2+1e-8f);
  float inv = 1.f/(w0+w1+w2);
  idx_out[p]          = i0;
  idx_out[p +  65536] = i1;
  idx_out[p + 131072] = i2;
  w_out[p]            = w0*inv;
  w_out[p +  65536]   = w1*inv;
  w_out[p + 131072]   = w2*inv;
}

// ---------------- K1.5: transpose feat2 -> feat2Tb[b][n2][c] bf16 ----------------
__global__ __launch_bounds__(256) void tr2_kernel(
    const float* __restrict__ feat2, u16* __restrict__ feat2Tb)
{
  __shared__ float sA[64][257];
  int b = blockIdx.y;
  int n0 = blockIdx.x * 64;
  int t = threadIdx.x;
  #pragma unroll
  for (int j = 0; j < 16; ++j) {
    int flat4 = t + j * 256;                       // 4096 float4s: 256c x 64n
    int c = flat4 >> 4, nn4 = (flat4 & 15) * 4;
    float4 v = *(const float4*)(feat2 + ((size_t)b*C2_ + c)*N2_ + n0 + nn4);
    sA[nn4+0][c] = v.x; sA[nn4+1][c] = v.y; sA[nn4+2][c] = v.z; sA[nn4+3][c] = v.w;
  }
  __syncthreads();
  int nn = t & 63, chunk = t >> 6;                 // 64 channels per thread
  u16* dst = feat2Tb + ((size_t)b*N2_ + n0 + nn)*C2_ + chunk*64;
  #pragma unroll
  for (int g = 0; g < 8; ++g) {
    u16 h8[8];
    #pragma unroll
    for (int j = 0; j < 8; ++j) h8[j] = f2bf(sA[nn][chunk*64 + g*8 + j]);
    *(uint4*)(dst + g*8) = pack8(h8);
  }
}

// ---------------- K2: fused prep (x<64: feat1 transpose | x>=64: 3NN interp) ----------------
__global__ __launch_bounds__(256) void prep_fused_kernel(
    const float* __restrict__ feat1, const u16* __restrict__ feat2Tb,
    const int* __restrict__ idx_in, const float* __restrict__ w_in,
    u16* __restrict__ xcatT)
{
  __shared__ float sA[64][133];
  int b = blockIdx.y;
  int t = threadIdx.x;
  if (blockIdx.x < 64) {
    // ---- feat1 transpose -> xcatT kt 0..3 ----
    int n0 = blockIdx.x * 64;
    #pragma unroll
    for (int j = 0; j < 8; ++j) {
      int flat4 = t + j * 256;                     // 2048 float4s: 128c x 64n
      int c = flat4 >> 4, nn4 = (flat4 & 15) * 4;
      float4 v = *(const float4*)(feat1 + ((size_t)b*C1_ + c)*N1_ + n0 + nn4);
      sA[nn4+0][c] = v.x; sA[nn4+1][c] = v.y; sA[nn4+2][c] = v.z; sA[nn4+3][c] = v.w;
    }
    __syncthreads();
    int nn = t & 63, chunk = t >> 6;
    int n = n0 + nn, nt = n >> 4, col = n & 15;
    u16* tb = xcatT + ((size_t)b*256 + nt)*12*512;
    #pragma unroll
    for (int g = 0; g < 4; ++g) {
      int c0 = chunk*32 + g*8;
      u16 h8[8];
      #pragma unroll
      for (int j = 0; j < 8; ++j) h8[j] = f2bf(sA[nn][c0 + j]);
      *(uint4*)(tb + (size_t)chunk*512 + (g*16 + col)*8) = pack8(h8);
    }
  } else {
    // ---- 3NN interpolate (bf16 gather) -> xcatT kt 4..11 ----
    int p0 = (blockIdx.x - 64) * 64;
    int seg = t & 31;                              // 8-channel segment
    int pl  = t >> 5;                              // 8 points per pass
    #pragma unroll 2
    for (int pass = 0; pass < 8; ++pass) {
      int n = p0 + pass*8 + pl;
      int base = b*N1_ + n;
      int i0 = idx_in[base], i1 = idx_in[base + 65536], i2 = idx_in[base + 131072];
      float w0 = w_in[base], w1 = w_in[base + 65536], w2 = w_in[base + 131072];
      const u16* fb = feat2Tb + (size_t)b*N2_*C2_ + seg*8;
      U128 a, c, d;
      a.u = *(const uint4*)(fb + (size_t)i0*C2_);
      c.u = *(const uint4*)(fb + (size_t)i1*C2_);
      d.u = *(const uint4*)(fb + (size_t)i2*C2_);
      u16 h8[8];
      #pragma unroll
      for (int j = 0; j < 8; ++j)
        h8[j] = f2bf(w0*bf2f(a.s[j]) + w1*bf2f(c.s[j]) + w2*bf2f(d.s[j]));
      int nt = n >> 4, col = n & 15;
      int kt = 4 + (seg >> 2), quad = seg & 3;
      *(uint4*)(xcatT + (((size_t)b*256 + nt)*12 + kt)*512 + (quad*16 + col)*8) = pack8(h8);
    }
  }
}

// ---------------- K3: GEMM1 MFMA, per-block partial stats (NO global atomics) ----------------
__global__ __launch_bounds__(256) void gemm1_mfma(
    const u16* __restrict__ xcatT, const u16* __restrict__ w0b,
    const float* __restrict__ b0p, u16* __restrict__ y0T,
    float* __restrict__ p0)
{
  __shared__ float ps[4][64][2];                   // [wave][ch64][sum|sq]
  int t = threadIdx.x;
  int wave = t >> 6, lane = t & 63;
  int col = lane & 15, quad = lane >> 4;
  int wm = wave >> 1, wn = wave & 1;
  int b = blockIdx.y;
  int mtb = blockIdx.z*8 + wm*4;
  int ntb = blockIdx.x*8 + wn*4;

  const u16* ap = w0b + lane*8;
  const u16* bp = xcatT + ((size_t)(b*256 + ntb)*12)*512 + lane*8;

  floatx4 acc[4][4] = {};
  bf16x8 af[4], bf[4], afn[4], bfn[4];
  #pragma unroll
  for (int i = 0; i < 4; ++i) {
    af[i] = ldfrag(ap + (size_t)((mtb+i)*12)*512);
    bf[i] = ldfrag(bp + (size_t)(i*12)*512);
  }
  #pragma unroll 1
  for (int kt = 1; kt < 12; ++kt) {
    #pragma unroll
    for (int i = 0; i < 4; ++i) afn[i] = ldfrag(ap + (size_t)((mtb+i)*12 + kt)*512);
    #pragma unroll
    for (int i = 0; i < 4; ++i) bfn[i] = ldfrag(bp + (size_t)(i*12 + kt)*512);
    #pragma unroll
    for (int mt = 0; mt < 4; ++mt)
      #pragma unroll
      for (int nt = 0; nt < 4; ++nt)
        acc[mt][nt] = __builtin_amdgcn_mfma_f32_16x16x32_bf16(af[mt], bf[nt], acc[mt][nt], 0, 0, 0);
    #pragma unroll
    for (int i = 0; i < 4; ++i) { af[i] = afn[i]; bf[i] = bfn[i]; }
  }
  #pragma unroll
  for (int mt = 0; mt < 4; ++mt)
    #pragma unroll
    for (int nt = 0; nt < 4; ++nt)
      acc[mt][nt] = __builtin_amdgcn_mfma_f32_16x16x32_bf16(af[mt], bf[nt], acc[mt][nt], 0, 0, 0);

  int m0 = blockIdx.z*128 + wm*64;
  #pragma unroll
  for (int mt = 0; mt < 4; ++mt) {
    float4 bias4 = *(const float4*)(b0p + m0 + mt*16 + quad*4);
    float bia[4] = {bias4.x, bias4.y, bias4.z, bias4.w};
    int kt_out = (m0 >> 5) + (mt >> 1);
    int quad_out = ((mt & 1) << 1) | (quad >> 1);
    int j0 = (quad & 1) * 4;
    float s[4] = {}, q[4] = {};
    #pragma unroll
    for (int nt = 0; nt < 4; ++nt) {
      int nt_g = ntb + nt;
      u16 h[4];
      #pragma unroll
      for (int r = 0; r < 4; ++r) {
        float v = acc[mt][nt][r] + bia[r];
        u16 hh = f2bf(v);
        float vr = bf2f(hh);
        h[r] = hh; s[r] += vr; q[r] += vr*vr;
      }
      *(ushort4*)(y0T + (((size_t)b*256 + nt_g)*8 + kt_out)*512 + (quad_out*16 + col)*8 + j0)
          = make_ushort4(h[0], h[1], h[2], h[3]);
    }
    #pragma unroll
    for (int r = 0; r < 4; ++r) {
      float ss = s[r], qq = q[r];
      #pragma unroll
      for (int msk = 1; msk < 16; msk <<= 1) { ss += __shfl_xor(ss, msk); qq += __shfl_xor(qq, msk); }
      if (col == 0) {
        ps[wave][mt*16 + quad*4 + r][0] = ss;
        ps[wave][mt*16 + quad*4 + r][1] = qq;
      }
    }
  }
  __syncthreads();
  {
    int c = t >> 1, k = t & 1;                     // c in [0,128)
    int wbase = (c >> 6) * 2, ch = c & 63;
    float v = ps[wbase][ch][k] + ps[wbase+1][ch][k];
    size_t l = (size_t)blockIdx.z*512 + blockIdx.y*32 + blockIdx.x;
    p0[l*256 + t] = v;
  }
}

// ---------------- K3.5: finalize stats -> scale/shift per channel ----------------
__global__ __launch_bounds__(256) void stats_kernel(
    const float* __restrict__ p, const float* __restrict__ g,
    const float* __restrict__ be, float* __restrict__ scale,
    float* __restrict__ shift, int half_split)
{
  int c = blockIdx.x, t = threadIdx.x;
  size_t base = half_split ? ((size_t)(c >> 7) * 512 * 256 + (size_t)(c & 127) * 2)
                           : ((size_t)c * 2);
  float s = 0.f, q = 0.f;
  #pragma unroll
  for (int i = 0; i < 2; ++i) {
    float2 v = *(const float2*)(p + base + (size_t)(t + i*256) * 256);
    s += v.x; q += v.y;
  }
  #pragma unroll
  for (int m = 1; m < 64; m <<= 1) { s += __shfl_xor(s, m); q += __shfl_xor(q, m); }
  __shared__ float2 red[4];
  if ((t & 63) == 0) red[t >> 6] = make_float2(s, q);
  __syncthreads();
  if (t == 0) {
    float ss = red[0].x + red[1].x + red[2].x + red[3].x;
    float qq = red[0].y + red[1].y + red[2].y + red[3].y;
    float mu  = ss * (1.f/65536.f);
    float var = qq * (1.f/65536.f) - mu*mu;
    float a = g[c] * rsqrtf(var + 1e-5f);
    scale[c] = a; shift[c] = be[c] - mu*a;
  }
}

// ---------------- K4: GEMM2 MFMA, BN0+ReLU fused on B-load, partial stats ----------------
__global__ __launch_bounds__(256) void gemm2_mfma(
    const u16* __restrict__ y0T, const u16* __restrict__ w1b,
    const float* __restrict__ b1p,
    const float* __restrict__ scale0, const float* __restrict__ shift0,
    float* __restrict__ out, float* __restrict__ p1)
{
  __shared__ float a0s[CM_], bb0s[CM_];
  __shared__ float ps[4][64][2];
  int t = threadIdx.x;
  a0s[t] = scale0[t]; bb0s[t] = shift0[t];
  __syncthreads();
  int wave = t >> 6, lane = t & 63;
  int col = lane & 15, quad = lane >> 4;
  int wm = wave >> 1, wn = wave & 1;
  int b = blockIdx.y;
  int mtb = wm*4;
  int ntb = blockIdx.x*8 + wn*4;

  const u16* ap = w1b + lane*8;
  const u16* bp = y0T + ((size_t)(b*256 + ntb)*8)*512 + lane*8;

  floatx4 acc[4][4] = {};
  bf16x8 af[4], afn[4];
  U128 braw[4], brawn[4];
  #pragma unroll
  for (int i = 0; i < 4; ++i) {
    af[i] = ldfrag(ap + (size_t)((mtb+i)*8)*512);
    braw[i].u = *(const uint4*)(bp + (size_t)(i*8)*512);
  }
  #pragma unroll 1
  for (int kt = 1; kt < 8; ++kt) {
    #pragma unroll
    for (int i = 0; i < 4; ++i) afn[i] = ldfrag(ap + (size_t)((mtb+i)*8 + kt)*512);
    #pragma unroll
    for (int i = 0; i < 4; ++i) brawn[i].u = *(const uint4*)(bp + (size_t)(i*8 + kt)*512);
    int c0 = (kt-1)*32 + quad*8;
    float4 av0 = *(const float4*)&a0s[c0], av1 = *(const float4*)&a0s[c0+4];
    float4 bv0 = *(const float4*)&bb0s[c0], bv1 = *(const float4*)&bb0s[c0+4];
    float av[8] = {av0.x,av0.y,av0.z,av0.w,av1.x,av1.y,av1.z,av1.w};
    float bv[8] = {bv0.x,bv0.y,bv0.z,bv0.w,bv1.x,bv1.y,bv1.z,bv1.w};
    bf16x8 bfv[4];
    #pragma unroll
    for (int i = 0; i < 4; ++i) {
      u16 h8[8];
      #pragma unroll
      for (int j = 0; j < 8; ++j)
        h8[j] = f2bf(fmaxf(fmaf(bf2f(braw[i].s[j]), av[j], bv[j]), 0.f));
      U128 x; x.u = pack8(h8); bfv[i] = x.v;
    }
    #pragma unroll
    for (int mt = 0; mt < 4; ++mt)
      #pragma unroll
      for (int nt = 0; nt < 4; ++nt)
        acc[mt][nt] = __builtin_amdgcn_mfma_f32_16x16x32_bf16(af[mt], bfv[nt], acc[mt][nt], 0, 0, 0);
    #pragma unroll
    for (int i = 0; i < 4; ++i) { af[i] = afn[i]; braw[i] = brawn[i]; }
  }
  {
    int c0 = 7*32 + quad*8;
    float4 av0 = *(const float4*)&a0s[c0], av1 = *(const float4*)&a0s[c0+4];
    float4 bv0 = *(const float4*)&bb0s[c0], bv1 = *(const float4*)&bb0s[c0+4];
    float av[8] = {av0.x,av0.y,av0.z,av0.w,av1.x,av1.y,av1.z,av1.w};
    float bv[8] = {bv0.x,bv0.y,bv0.z,bv0.w,bv1.x,bv1.y,bv1.z,bv1.w};
    bf16x8 bfv[4];
    #pragma unroll
    for (int i = 0; i < 4; ++i) {
      u16 h8[8];
      #pragma unroll
      for (int j = 0; j < 8; ++j)
        h8[j] = f2bf(fmaxf(fmaf(bf2f(braw[i].s[j]), av[j], bv[j]), 0.f));
      U128 x; x.u = pack8(h8); bfv[i] = x.v;
    }
    #pragma unroll
    for (int mt = 0; mt < 4; ++mt)
      #pragma unroll
      for (int nt = 0; nt < 4; ++nt)
        acc[mt][nt] = __builtin_amdgcn_mfma_f32_16x16x32_bf16(af[mt], bfv[nt], acc[mt][nt], 0, 0, 0);
  }

  int m0 = wm*64;
  int n0 = blockIdx.x*128 + wn*64;
  #pragma unroll
  for (int mt = 0; mt < 4; ++mt) {
    float4 bias4 = *(const float4*)(b1p + m0 + mt*16 + quad*4);
    float bia[4] = {bias4.x, bias4.y, bias4.z, bias4.w};
    float s[4] = {}, q[4] = {};
    #pragma unroll
    for (int nt = 0; nt < 4; ++nt) {
      int n = n0 + nt*16 + col;
      #pragma unroll
      for (int r = 0; r < 4; ++r) {
        float v = acc[mt][nt][r] + bia[r];
        out[((size_t)b*CO_ + m0 + mt*16 + quad*4 + r)*N1_ + n] = v;
        s[r] += v; q[r] += v*v;
      }
    }
    #pragma unroll
    for (int r = 0; r < 4; ++r) {
      float ss = s[r], qq = q[r];
      #pragma unroll
      for (int msk = 1; msk < 16; msk <<= 1) { ss += __shfl_xor(ss, msk); qq += __shfl_xor(qq, msk); }
      if (col == 0) {
        ps[wave][mt*16 + quad*4 + r][0] = ss;
        ps[wave][mt*16 + quad*4 + r][1] = qq;
      }
    }
  }
  __syncthreads();
  {
    int c = t >> 1, k = t & 1;
    int wbase = (c >> 6) * 2, ch = c & 63;
    float v = ps[wbase][ch][k] + ps[wbase+1][ch][k];
    size_t l = (size_t)blockIdx.y*32 + blockIdx.x;
    p1[l*256 + t] = v;
  }
}

// ---------------- K5: BN1 + ReLU in place on d_out ----------------
__global__ __launch_bounds__(256) void bnrelu_kernel(
    float* __restrict__ out, const float* __restrict__ scale1, const float* __restrict__ shift1)
{
  int idx = blockIdx.x * 256 + threadIdx.x;   // float4 index
  int c = (idx >> 10) & (CO_ - 1);
  float a = scale1[c];
  float bb = shift1[c];
  float4 v = ((const float4*)out)[idx];
  v.x = fmaxf(fmaf(v.x, a, bb), 0.f);
  v.y = fmaxf(fmaf(v.y, a, bb), 0.f);
  v.z = fmaxf(fmaf(v.z, a, bb), 0.f);
  v.w = fmaxf(fmaf(v.w, a, bb), 0.f);
  ((float4*)out)[idx] = v;
}

extern "C" void kernel_launch(void* const* d_in, const int* in_sizes, int n_in,
                              void* d_out, int out_size, void* d_ws, size_t ws_size,
                              hipStream_t stream)
{
  const float* xyz1  = (const float*)d_in[0];
  const float* xyz2  = (const float*)d_in[1];
  const float* feat1 = (const float*)d_in[2];
  const float* feat2 = (const float*)d_in[3];
  const float* w0    = (const float*)d_in[4];
  const float* b0    = (const float*)d_in[5];
  const float* g0    = (const float*)d_in[6];
  const float* be0   = (const float*)d_in[7];
  const float* w1    = (const float*)d_in[8];
  const float* b1    = (const float*)d_in[9];
  const float* g1    = (const float*)d_in[10];
  const float* be1   = (const float*)d_in[11];
  float* out = (float*)d_out;
  char* ws = (char*)d_ws;

  // workspace layout (bytes)
  u16*   xcatT   = (u16*)ws;                                   // 50331648
  float* knn_pd  = (float*)ws;                                 // 6291456 (alias xcatT; dead before prep)
  int*   knn_pi  = (int*)(ws + 6291456);                       // 6291456
  u16*   y0T     = (u16*)(ws + 50331648);                      // 33554432
  u16*   feat2Tb = (u16*)(ws + 50331648);                      // 8 MB (alias y0T, dead before gemm1)
  u16*   w0b     = (u16*)(ws + 83886080);                      // 196608
  u16*   w1b     = (u16*)(ws + 84082688);                      // 65536
  int*   idx_buf = (int*)(ws + 84148224);                      // 786432
  float* w_buf   = (float*)(ws + 84934656);                    // 786432
  float* p0      = (float*)(ws + 85721088);                    // 1048576
  float* p1      = (float*)(ws + 86769664);                    // 524288
  float* scale0  = (float*)(ws + 87293952);                    // 256
  float* shift0  = scale0 + 256;
  float* scale1  = scale0 + 512;
  float* shift1  = scale0 + 640;

  knn_part_kernel <<<dim3(5,16,8),    256, 0, stream>>>(xyz1, xyz2, knn_pd, knn_pi, w0, w1, w0b, w1b);
  knn_merge_kernel<<<256,             256, 0, stream>>>(knn_pd, knn_pi, idx_buf, w_buf);
  tr2_kernel      <<<dim3(16,16),     256, 0, stream>>>(feat2, feat2Tb);
  prep_fused_kernel<<<dim3(128,16),   256, 0, stream>>>(feat1, feat2Tb, idx_buf, w_buf, xcatT);
  gemm1_mfma      <<<dim3(32,16,2),   256, 0, stream>>>(xcatT, w0b, b0, y0T, p0);
  stats_kernel    <<<256,             256, 0, stream>>>(p0, g0, be0, scale0, shift0, 1);
  gemm2_mfma      <<<dim3(32,16),     256, 0, stream>>>(y0T, w1b, b1, scale0, shift0, out, p1);
  stats_kernel    <<<128,             256, 0, stream>>>(p1, g1, be1, scale1, shift1, 0);
  bnrelu_kernel   <<<8192,            256, 0, stream>>>(out, scale1, shift1);
}

// Round 8
// 250.789 us; speedup vs baseline: 1.0999x; 1.0999x over previous
//
#include <hip/hip_runtime.h>
#include <hip/hip_bf16.h>

typedef unsigned short u16;
typedef __attribute__((ext_vector_type(8))) __bf16 bf16x8;
typedef __attribute__((ext_vector_type(4))) float floatx4;

#define B_   16
#define N1_  4096
#define N2_  1024
#define C1_  128
#define C2_  256
#define CIN_ 384
#define CM_  256
#define CO_  128

__device__ __forceinline__ u16 f2bf(float f) {
  unsigned u = __float_as_uint(f);
  u = (u + 0x7fffu + ((u >> 16) & 1u)) >> 16;
  return (u16)u;
}
__device__ __forceinline__ float bf2f(u16 h) {
  return __uint_as_float(((unsigned)h) << 16);
}

union U128 { uint4 u; bf16x8 v; u16 s[8]; };

__device__ __forceinline__ bf16x8 ldfrag(const u16* p) {
  U128 x; x.u = *(const uint4*)p; return x.v;
}
__device__ __forceinline__ uint4 pack8(const u16* h) {
  uint4 u;
  u.x = (unsigned)h[0] | ((unsigned)h[1] << 16);
  u.y = (unsigned)h[2] | ((unsigned)h[3] << 16);
  u.z = (unsigned)h[4] | ((unsigned)h[5] << 16);
  u.w = (unsigned)h[6] | ((unsigned)h[7] << 16);
  return u;
}

// Tiled operand layout (MFMA-fragment-major):
//   frag(tile, kt) at [tile][kt][lane][8] u16, lane = quad*16+col,
//   element j = M[row=col][k = kt*32 + quad*8 + j]. Wave frag load = base + lane*16B.

// ---------------- K1a: 3-NN partial (128-cand chunk, 1 pt/thread, if-chain insert)
//                  + castw side-job ----------------
// grid (17,16,8): x<16 -> knn (x = 256-point block, y = batch, z = 128-cand chunk);
//                 x==16 -> weight cast (128 blocks, items 0..16383).
__global__ __launch_bounds__(256) void knn_part_kernel(
    const float* __restrict__ xyz1, const float* __restrict__ xyz2,
    float* __restrict__ pd, int* __restrict__ pi,
    const float* __restrict__ w0, const float* __restrict__ w1,
    u16* __restrict__ w0b, u16* __restrict__ w1b)
{
  __shared__ float4 sp[128];
  int t = threadIdx.x;
  if (blockIdx.x == 16) {                          // ---- castw side-job ----
    int item = (blockIdx.y * 8 + blockIdx.z) * 256 + t;   // 0..32767
    if (item < 12288) {                             // w0: 256 rows x 48 chunks
      int m = item / 48, kc = item % 48;
      const float* p = w0 + m * CIN_ + kc * 8;
      u16 h8[8];
      #pragma unroll
      for (int j = 0; j < 8; ++j) h8[j] = f2bf(p[j]);
      int mt = m >> 4, col = m & 15, kt = kc >> 2, quad = kc & 3;
      *(uint4*)(w0b + ((mt*12 + kt)*512 + (quad*16 + col)*8)) = pack8(h8);
    } else if (item < 16384) {                      // w1: 128 rows x 32 chunks
      int i2 = item - 12288;
      int m = i2 >> 5, kc = i2 & 31;
      const float* p = w1 + m * CM_ + kc * 8;
      u16 h8[8];
      #pragma unroll
      for (int j = 0; j < 8; ++j) h8[j] = f2bf(p[j]);
      int mt = m >> 4, col = m & 15, kt = kc >> 2, quad = kc & 3;
      *(uint4*)(w1b + ((mt*8 + kt)*512 + (quad*16 + col)*8)) = pack8(h8);
    }
    return;
  }
  // ---- knn: one point/thread, 128 candidates ----
  int b = blockIdx.y, chunk = blockIdx.z;
  const float* p2 = xyz2 + ((size_t)b * N2_ + chunk * 128) * 3;
  if (t < 128) sp[t] = make_float4(p2[t*3], p2[t*3+1], p2[t*3+2], 0.f);
  __syncthreads();
  int i = blockIdx.x * 256 + t;
  const float* p1 = xyz1 + ((size_t)b * N1_ + i) * 3;
  float x = p1[0], y = p1[1], z = p1[2];
  float d0 = 1e30f, d1 = 1e30f, d2 = 1e30f;
  int i0 = 0, i1 = 0, i2 = 0;
  int jb = chunk * 128;
  #pragma unroll 4
  for (int j = 0; j < 128; ++j) {
    float4 p = sp[j];                              // broadcast: conflict-free
    float dx = x - p.x, dy = y - p.y, dz = z - p.z;
    float d = dx*dx + dy*dy + dz*dz;
    if (d < d2) {                                  // strict <: stable (earlier j wins ties)
      int jj = jb + j;
      if (d < d0)      { d2=d1; i2=i1; d1=d0; i1=i0; d0=d; i0=jj; }
      else if (d < d1) { d2=d1; i2=i1; d1=d;  i1=jj; }
      else             { d2=d;  i2=jj; }
    }
  }
  int o = chunk*65536 + b*4096 + i;
  pd[o] = d0; pd[o + 524288] = d1; pd[o + 1048576] = d2;
  pi[o] = i0; pi[o + 524288] = i1; pi[o + 1048576] = i2;
}

// ---------------- K1b: merge 8 chunk-triples -> final idx/weights ----------------
__global__ __launch_bounds__(256) void knn_merge_kernel(
    const float* __restrict__ pd, const int* __restrict__ pi,
    int* __restrict__ idx_out, float* __restrict__ w_out)
{
  int p = blockIdx.x * 256 + threadIdx.x;          // p = b*4096 + i, 0..65535
  float d0 = 1e30f, d1 = 1e30f, d2 = 1e30f;
  int i0 = 0, i1 = 0, i2 = 0;
  #pragma unroll
  for (int c = 0; c < 8; ++c) {                    // ascending-j chunk order: stable
    int o = c*65536 + p;
    #pragma unroll
    for (int k = 0; k < 3; ++k) {
      float d = pd[o + k*524288];
      int ix = pi[o + k*524288];
      if (d < d2) {
        if (d < d0)      { d2=d1; i2=i1; d1=d0; i1=i0; d0=d; i0=ix; }
        else if (d < d1) { d2=d1; i2=i1; d1=d;  i1=ix; }
        else             { d2=d;  i2=ix; }
      }
    }
  }
  float w0 = 1.f/(d0+1e-8f), w1 = 1.f/(d1+1e-8f), w2 = 1.f/(d2+1e-8f);
  float inv = 1.f/(w0+w1+w2);
  idx_out[p]          = i0;
  idx_out[p +  65536] = i1;
  idx_out[p + 131072] = i2;
  w_out[p]            = w0*inv;
  w_out[p +  65536]   = w1*inv;
  w_out[p + 131072]   = w2*inv;
}

// ---------------- K1.5: transpose feat2 -> feat2Tb[b][n2][c] bf16 ----------------
__global__ __launch_bounds__(256) void tr2_kernel(
    const float* __restrict__ feat2, u16* __restrict__ feat2Tb)
{
  __shared__ float sA[64][257];
  int b = blockIdx.y;
  int n0 = blockIdx.x * 64;
  int t = threadIdx.x;
  #pragma unroll
  for (int j = 0; j < 16; ++j) {
    int flat4 = t + j * 256;                       // 4096 float4s: 256c x 64n
    int c = flat4 >> 4, nn4 = (flat4 & 15) * 4;
    float4 v = *(const float4*)(feat2 + ((size_t)b*C2_ + c)*N2_ + n0 + nn4);
    sA[nn4+0][c] = v.x; sA[nn4+1][c] = v.y; sA[nn4+2][c] = v.z; sA[nn4+3][c] = v.w;
  }
  __syncthreads();
  int nn = t & 63, chunk = t >> 6;                 // 64 channels per thread
  u16* dst = feat2Tb + ((size_t)b*N2_ + n0 + nn)*C2_ + chunk*64;
  #pragma unroll
  for (int g = 0; g < 8; ++g) {
    u16 h8[8];
    #pragma unroll
    for (int j = 0; j < 8; ++j) h8[j] = f2bf(sA[nn][chunk*64 + g*8 + j]);
    *(uint4*)(dst + g*8) = pack8(h8);
  }
}

// ---------------- K2: fused prep (x<64: feat1 transpose | x>=64: 3NN interp) ----------------
__global__ __launch_bounds__(256) void prep_fused_kernel(
    const float* __restrict__ feat1, const u16* __restrict__ feat2Tb,
    const int* __restrict__ idx_in, const float* __restrict__ w_in,
    u16* __restrict__ xcatT)
{
  __shared__ float sA[64][133];
  int b = blockIdx.y;
  int t = threadIdx.x;
  if (blockIdx.x < 64) {
    // ---- feat1 transpose -> xcatT kt 0..3 ----
    int n0 = blockIdx.x * 64;
    #pragma unroll
    for (int j = 0; j < 8; ++j) {
      int flat4 = t + j * 256;                     // 2048 float4s: 128c x 64n
      int c = flat4 >> 4, nn4 = (flat4 & 15) * 4;
      float4 v = *(const float4*)(feat1 + ((size_t)b*C1_ + c)*N1_ + n0 + nn4);
      sA[nn4+0][c] = v.x; sA[nn4+1][c] = v.y; sA[nn4+2][c] = v.z; sA[nn4+3][c] = v.w;
    }
    __syncthreads();
    int nn = t & 63, chunk = t >> 6;
    int n = n0 + nn, nt = n >> 4, col = n & 15;
    u16* tb = xcatT + ((size_t)b*256 + nt)*12*512;
    #pragma unroll
    for (int g = 0; g < 4; ++g) {
      int c0 = chunk*32 + g*8;
      u16 h8[8];
      #pragma unroll
      for (int j = 0; j < 8; ++j) h8[j] = f2bf(sA[nn][c0 + j]);
      *(uint4*)(tb + (size_t)chunk*512 + (g*16 + col)*8) = pack8(h8);
    }
  } else {
    // ---- 3NN interpolate (bf16 gather) -> xcatT kt 4..11 ----
    int p0 = (blockIdx.x - 64) * 64;
    int seg = t & 31;                              // 8-channel segment
    int pl  = t >> 5;                              // 8 points per pass
    #pragma unroll 2
    for (int pass = 0; pass < 8; ++pass) {
      int n = p0 + pass*8 + pl;
      int base = b*N1_ + n;
      int i0 = idx_in[base], i1 = idx_in[base + 65536], i2 = idx_in[base + 131072];
      float w0 = w_in[base], w1 = w_in[base + 65536], w2 = w_in[base + 131072];
      const u16* fb = feat2Tb + (size_t)b*N2_*C2_ + seg*8;
      U128 a, c, d;
      a.u = *(const uint4*)(fb + (size_t)i0*C2_);
      c.u = *(const uint4*)(fb + (size_t)i1*C2_);
      d.u = *(const uint4*)(fb + (size_t)i2*C2_);
      u16 h8[8];
      #pragma unroll
      for (int j = 0; j < 8; ++j)
        h8[j] = f2bf(w0*bf2f(a.s[j]) + w1*bf2f(c.s[j]) + w2*bf2f(d.s[j]));
      int nt = n >> 4, col = n & 15;
      int kt = 4 + (seg >> 2), quad = seg & 3;
      *(uint4*)(xcatT + (((size_t)b*256 + nt)*12 + kt)*512 + (quad*16 + col)*8) = pack8(h8);
    }
  }
}

// ---------------- K3: GEMM1 MFMA, per-block partial stats (NO global atomics) ----------------
__global__ __launch_bounds__(256) void gemm1_mfma(
    const u16* __restrict__ xcatT, const u16* __restrict__ w0b,
    const float* __restrict__ b0p, u16* __restrict__ y0T,
    float* __restrict__ p0)
{
  __shared__ float ps[4][64][2];                   // [wave][ch64][sum|sq]
  int t = threadIdx.x;
  int wave = t >> 6, lane = t & 63;
  int col = lane & 15, quad = lane >> 4;
  int wm = wave >> 1, wn = wave & 1;
  int b = blockIdx.y;
  int mtb = blockIdx.z*8 + wm*4;
  int ntb = blockIdx.x*8 + wn*4;

  const u16* ap = w0b + lane*8;
  const u16* bp = xcatT + ((size_t)(b*256 + ntb)*12)*512 + lane*8;

  floatx4 acc[4][4] = {};
  bf16x8 af[4], bf[4], afn[4], bfn[4];
  #pragma unroll
  for (int i = 0; i < 4; ++i) {
    af[i] = ldfrag(ap + (size_t)((mtb+i)*12)*512);
    bf[i] = ldfrag(bp + (size_t)(i*12)*512);
  }
  #pragma unroll 1
  for (int kt = 1; kt < 12; ++kt) {
    #pragma unroll
    for (int i = 0; i < 4; ++i) afn[i] = ldfrag(ap + (size_t)((mtb+i)*12 + kt)*512);
    #pragma unroll
    for (int i = 0; i < 4; ++i) bfn[i] = ldfrag(bp + (size_t)(i*12 + kt)*512);
    #pragma unroll
    for (int mt = 0; mt < 4; ++mt)
      #pragma unroll
      for (int nt = 0; nt < 4; ++nt)
        acc[mt][nt] = __builtin_amdgcn_mfma_f32_16x16x32_bf16(af[mt], bf[nt], acc[mt][nt], 0, 0, 0);
    #pragma unroll
    for (int i = 0; i < 4; ++i) { af[i] = afn[i]; bf[i] = bfn[i]; }
  }
  #pragma unroll
  for (int mt = 0; mt < 4; ++mt)
    #pragma unroll
    for (int nt = 0; nt < 4; ++nt)
      acc[mt][nt] = __builtin_amdgcn_mfma_f32_16x16x32_bf16(af[mt], bf[nt], acc[mt][nt], 0, 0, 0);

  int m0 = blockIdx.z*128 + wm*64;
  #pragma unroll
  for (int mt = 0; mt < 4; ++mt) {
    float4 bias4 = *(const float4*)(b0p + m0 + mt*16 + quad*4);
    float bia[4] = {bias4.x, bias4.y, bias4.z, bias4.w};
    int kt_out = (m0 >> 5) + (mt >> 1);
    int quad_out = ((mt & 1) << 1) | (quad >> 1);
    int j0 = (quad & 1) * 4;
    float s[4] = {}, q[4] = {};
    #pragma unroll
    for (int nt = 0; nt < 4; ++nt) {
      int nt_g = ntb + nt;
      u16 h[4];
      #pragma unroll
      for (int r = 0; r < 4; ++r) {
        float v = acc[mt][nt][r] + bia[r];
        u16 hh = f2bf(v);
        float vr = bf2f(hh);
        h[r] = hh; s[r] += vr; q[r] += vr*vr;
      }
      *(ushort4*)(y0T + (((size_t)b*256 + nt_g)*8 + kt_out)*512 + (quad_out*16 + col)*8 + j0)
          = make_ushort4(h[0], h[1], h[2], h[3]);
    }
    #pragma unroll
    for (int r = 0; r < 4; ++r) {
      float ss = s[r], qq = q[r];
      #pragma unroll
      for (int msk = 1; msk < 16; msk <<= 1) { ss += __shfl_xor(ss, msk); qq += __shfl_xor(qq, msk); }
      if (col == 0) {
        ps[wave][mt*16 + quad*4 + r][0] = ss;
        ps[wave][mt*16 + quad*4 + r][1] = qq;
      }
    }
  }
  __syncthreads();
  {
    int c = t >> 1, k = t & 1;                     // c in [0,128)
    int wbase = (c >> 6) * 2, ch = c & 63;
    float v = ps[wbase][ch][k] + ps[wbase+1][ch][k];
    size_t l = (size_t)blockIdx.z*512 + blockIdx.y*32 + blockIdx.x;
    p0[l*256 + t] = v;
  }
}

// ---------------- K3.5: finalize stats -> scale/shift per channel ----------------
__global__ __launch_bounds__(256) void stats_kernel(
    const float* __restrict__ p, const float* __restrict__ g,
    const float* __restrict__ be, float* __restrict__ scale,
    float* __restrict__ shift, int half_split)
{
  int c = blockIdx.x, t = threadIdx.x;
  size_t base = half_split ? ((size_t)(c >> 7) * 512 * 256 + (size_t)(c & 127) * 2)
                           : ((size_t)c * 2);
  float s = 0.f, q = 0.f;
  #pragma unroll
  for (int i = 0; i < 2; ++i) {
    float2 v = *(const float2*)(p + base + (size_t)(t + i*256) * 256);
    s += v.x; q += v.y;
  }
  #pragma unroll
  for (int m = 1; m < 64; m <<= 1) { s += __shfl_xor(s, m); q += __shfl_xor(q, m); }
  __shared__ float2 red[4];
  if ((t & 63) == 0) red[t >> 6] = make_float2(s, q);
  __syncthreads();
  if (t == 0) {
    float ss = red[0].x + red[1].x + red[2].x + red[3].x;
    float qq = red[0].y + red[1].y + red[2].y + red[3].y;
    float mu  = ss * (1.f/65536.f);
    float var = qq * (1.f/65536.f) - mu*mu;
    float a = g[c] * rsqrtf(var + 1e-5f);
    scale[c] = a; shift[c] = be[c] - mu*a;
  }
}

// ---------------- K4: GEMM2 MFMA, BN0+ReLU fused on B-load, partial stats ----------------
__global__ __launch_bounds__(256) void gemm2_mfma(
    const u16* __restrict__ y0T, const u16* __restrict__ w1b,
    const float* __restrict__ b1p,
    const float* __restrict__ scale0, const float* __restrict__ shift0,
    float* __restrict__ out, float* __restrict__ p1)
{
  __shared__ float a0s[CM_], bb0s[CM_];
  __shared__ float ps[4][64][2];
  int t = threadIdx.x;
  a0s[t] = scale0[t]; bb0s[t] = shift0[t];
  __syncthreads();
  int wave = t >> 6, lane = t & 63;
  int col = lane & 15, quad = lane >> 4;
  int wm = wave >> 1, wn = wave & 1;
  int b = blockIdx.y;
  int mtb = wm*4;
  int ntb = blockIdx.x*8 + wn*4;

  const u16* ap = w1b + lane*8;
  const u16* bp = y0T + ((size_t)(b*256 + ntb)*8)*512 + lane*8;

  floatx4 acc[4][4] = {};
  bf16x8 af[4], afn[4];
  U128 braw[4], brawn[4];
  #pragma unroll
  for (int i = 0; i < 4; ++i) {
    af[i] = ldfrag(ap + (size_t)((mtb+i)*8)*512);
    braw[i].u = *(const uint4*)(bp + (size_t)(i*8)*512);
  }
  #pragma unroll 1
  for (int kt = 1; kt < 8; ++kt) {
    #pragma unroll
    for (int i = 0; i < 4; ++i) afn[i] = ldfrag(ap + (size_t)((mtb+i)*8 + kt)*512);
    #pragma unroll
    for (int i = 0; i < 4; ++i) brawn[i].u = *(const uint4*)(bp + (size_t)(i*8 + kt)*512);
    int c0 = (kt-1)*32 + quad*8;
    float4 av0 = *(const float4*)&a0s[c0], av1 = *(const float4*)&a0s[c0+4];
    float4 bv0 = *(const float4*)&bb0s[c0], bv1 = *(const float4*)&bb0s[c0+4];
    float av[8] = {av0.x,av0.y,av0.z,av0.w,av1.x,av1.y,av1.z,av1.w};
    float bv[8] = {bv0.x,bv0.y,bv0.z,bv0.w,bv1.x,bv1.y,bv1.z,bv1.w};
    bf16x8 bfv[4];
    #pragma unroll
    for (int i = 0; i < 4; ++i) {
      u16 h8[8];
      #pragma unroll
      for (int j = 0; j < 8; ++j)
        h8[j] = f2bf(fmaxf(fmaf(bf2f(braw[i].s[j]), av[j], bv[j]), 0.f));
      U128 x; x.u = pack8(h8); bfv[i] = x.v;
    }
    #pragma unroll
    for (int mt = 0; mt < 4; ++mt)
      #pragma unroll
      for (int nt = 0; nt < 4; ++nt)
        acc[mt][nt] = __builtin_amdgcn_mfma_f32_16x16x32_bf16(af[mt], bfv[nt], acc[mt][nt], 0, 0, 0);
    #pragma unroll
    for (int i = 0; i < 4; ++i) { af[i] = afn[i]; braw[i] = brawn[i]; }
  }
  {
    int c0 = 7*32 + quad*8;
    float4 av0 = *(const float4*)&a0s[c0], av1 = *(const float4*)&a0s[c0+4];
    float4 bv0 = *(const float4*)&bb0s[c0], bv1 = *(const float4*)&bb0s[c0+4];
    float av[8] = {av0.x,av0.y,av0.z,av0.w,av1.x,av1.y,av1.z,av1.w};
    float bv[8] = {bv0.x,bv0.y,bv0.z,bv0.w,bv1.x,bv1.y,bv1.z,bv1.w};
    bf16x8 bfv[4];
    #pragma unroll
    for (int i = 0; i < 4; ++i) {
      u16 h8[8];
      #pragma unroll
      for (int j = 0; j < 8; ++j)
        h8[j] = f2bf(fmaxf(fmaf(bf2f(braw[i].s[j]), av[j], bv[j]), 0.f));
      U128 x; x.u = pack8(h8); bfv[i] = x.v;
    }
    #pragma unroll
    for (int mt = 0; mt < 4; ++mt)
      #pragma unroll
      for (int nt = 0; nt < 4; ++nt)
        acc[mt][nt] = __builtin_amdgcn_mfma_f32_16x16x32_bf16(af[mt], bfv[nt], acc[mt][nt], 0, 0, 0);
  }

  int m0 = wm*64;
  int n0 = blockIdx.x*128 + wn*64;
  #pragma unroll
  for (int mt = 0; mt < 4; ++mt) {
    float4 bias4 = *(const float4*)(b1p + m0 + mt*16 + quad*4);
    float bia[4] = {bias4.x, bias4.y, bias4.z, bias4.w};
    float s[4] = {}, q[4] = {};
    #pragma unroll
    for (int nt = 0; nt < 4; ++nt) {
      int n = n0 + nt*16 + col;
      #pragma unroll
      for (int r = 0; r < 4; ++r) {
        float v = acc[mt][nt][r] + bia[r];
        out[((size_t)b*CO_ + m0 + mt*16 + quad*4 + r)*N1_ + n] = v;
        s[r] += v; q[r] += v*v;
      }
    }
    #pragma unroll
    for (int r = 0; r < 4; ++r) {
      float ss = s[r], qq = q[r];
      #pragma unroll
      for (int msk = 1; msk < 16; msk <<= 1) { ss += __shfl_xor(ss, msk); qq += __shfl_xor(qq, msk); }
      if (col == 0) {
        ps[wave][mt*16 + quad*4 + r][0] = ss;
        ps[wave][mt*16 + quad*4 + r][1] = qq;
      }
    }
  }
  __syncthreads();
  {
    int c = t >> 1, k = t & 1;
    int wbase = (c >> 6) * 2, ch = c & 63;
    float v = ps[wbase][ch][k] + ps[wbase+1][ch][k];
    size_t l = (size_t)blockIdx.y*32 + blockIdx.x;
    p1[l*256 + t] = v;
  }
}

// ---------------- K5: BN1 + ReLU in place on d_out ----------------
__global__ __launch_bounds__(256) void bnrelu_kernel(
    float* __restrict__ out, const float* __restrict__ scale1, const float* __restrict__ shift1)
{
  int idx = blockIdx.x * 256 + threadIdx.x;   // float4 index
  int c = (idx >> 10) & (CO_ - 1);
  float a = scale1[c];
  float bb = shift1[c];
  float4 v = ((const float4*)out)[idx];
  v.x = fmaxf(fmaf(v.x, a, bb), 0.f);
  v.y = fmaxf(fmaf(v.y, a, bb), 0.f);
  v.z = fmaxf(fmaf(v.z, a, bb), 0.f);
  v.w = fmaxf(fmaf(v.w, a, bb), 0.f);
  ((float4*)out)[idx] = v;
}

extern "C" void kernel_launch(void* const* d_in, const int* in_sizes, int n_in,
                              void* d_out, int out_size, void* d_ws, size_t ws_size,
                              hipStream_t stream)
{
  const float* xyz1  = (const float*)d_in[0];
  const float* xyz2  = (const float*)d_in[1];
  const float* feat1 = (const float*)d_in[2];
  const float* feat2 = (const float*)d_in[3];
  const float* w0    = (const float*)d_in[4];
  const float* b0    = (const float*)d_in[5];
  const float* g0    = (const float*)d_in[6];
  const float* be0   = (const float*)d_in[7];
  const float* w1    = (const float*)d_in[8];
  const float* b1    = (const float*)d_in[9];
  const float* g1    = (const float*)d_in[10];
  const float* be1   = (const float*)d_in[11];
  float* out = (float*)d_out;
  char* ws = (char*)d_ws;

  // workspace layout (bytes)
  u16*   xcatT   = (u16*)ws;                                   // 50331648
  float* knn_pd  = (float*)ws;                                 // 6291456 (alias xcatT; dead before prep)
  int*   knn_pi  = (int*)(ws + 6291456);                       // 6291456
  u16*   y0T     = (u16*)(ws + 50331648);                      // 33554432
  u16*   feat2Tb = (u16*)(ws + 50331648);                      // 8 MB (alias y0T, dead before gemm1)
  u16*   w0b     = (u16*)(ws + 83886080);                      // 196608
  u16*   w1b     = (u16*)(ws + 84082688);                      // 65536
  int*   idx_buf = (int*)(ws + 84148224);                      // 786432
  float* w_buf   = (float*)(ws + 84934656);                    // 786432
  float* p0      = (float*)(ws + 85721088);                    // 1048576
  float* p1      = (float*)(ws + 86769664);                    // 524288
  float* scale0  = (float*)(ws + 87293952);                    // 256
  float* shift0  = scale0 + 256;
  float* scale1  = scale0 + 512;
  float* shift1  = scale0 + 640;

  knn_part_kernel <<<dim3(17,16,8),   256, 0, stream>>>(xyz1, xyz2, knn_pd, knn_pi, w0, w1, w0b, w1b);
  knn_merge_kernel<<<256,             256, 0, stream>>>(knn_pd, knn_pi, idx_buf, w_buf);
  tr2_kernel      <<<dim3(16,16),     256, 0, stream>>>(feat2, feat2Tb);
  prep_fused_kernel<<<dim3(128,16),   256, 0, stream>>>(feat1, feat2Tb, idx_buf, w_buf, xcatT);
  gemm1_mfma      <<<dim3(32,16,2),   256, 0, stream>>>(xcatT, w0b, b0, y0T, p0);
  stats_kernel    <<<256,             256, 0, stream>>>(p0, g0, be0, scale0, shift0, 1);
  gemm2_mfma      <<<dim3(32,16),     256, 0, stream>>>(y0T, w1b, b1, scale0, shift0, out, p1);
  stats_kernel    <<<128,             256, 0, stream>>>(p1, g1, be1, scale1, shift1, 0);
  bnrelu_kernel   <<<8192,            256, 0, stream>>>(out, scale1, shift1);
}